// Round 3
// baseline (365.087 us; speedup 1.0000x reference)
//
#include <hip/hip_runtime.h>
#include <hip/hip_bf16.h>

#define IN_DIM 128
#define HID 24
#define OUT_DIM 4096
#define NB 16384
#define KMOV 256

// ---------------- Kernel A: transpose W3 [24,4096] -> W3T [4096,24] ----------
__global__ __launch_bounds__(256) void ktranspose(const float* __restrict__ W3,
                                                  float* __restrict__ W3T) {
    int t = blockIdx.x * 256 + threadIdx.x;
    if (t < OUT_DIM * HID) {
        int c = t / HID;
        int k = t - c * HID;
        W3T[t] = W3[k * OUT_DIM + c];   // W3T[c*24+k] = W3[k][c]
    }
}

// ---------------- Kernel B: h2 = relu(relu(x@W1+b1)@W2+b2) -------------------
// 8 rows per 256-thread block; 32-thread group per row, lanes 0..23 active.
__global__ __launch_bounds__(256) void kmlp(const float* __restrict__ x,
                                            const float* __restrict__ W1,
                                            const float* __restrict__ b1,
                                            const float* __restrict__ W2,
                                            const float* __restrict__ b2,
                                            float* __restrict__ h2out) {
    __shared__ float W1s[IN_DIM * HID];   // 12 KB
    __shared__ float W2s[HID * HID];
    __shared__ float b1s[HID], b2s[HID];
    __shared__ float xs[8][IN_DIM];       // 4 KB

    int t = threadIdx.x;
    for (int i = t; i < IN_DIM * HID; i += 256) W1s[i] = W1[i];
    for (int i = t; i < HID * HID; i += 256)    W2s[i] = W2[i];
    if (t < HID) { b1s[t] = b1[t]; b2s[t] = b2[t]; }
    int rbase = blockIdx.x * 8;
    for (int i = t; i < 8 * IN_DIM; i += 256)
        xs[i >> 7][i & 127] = x[(size_t)rbase * IN_DIM + i];
    __syncthreads();

    int g = t >> 5;        // row group 0..7
    int j = t & 31;        // lane within group
    int r = rbase + g;

    float h1 = 0.f;
    if (j < HID) {
        h1 = b1s[j];
        #pragma unroll 8
        for (int i = 0; i < IN_DIM; i++) h1 += xs[g][i] * W1s[i * HID + j];
        h1 = fmaxf(h1, 0.f);
    }
    float h2 = (j < HID) ? b2s[j] : 0.f;
    #pragma unroll
    for (int k = 0; k < HID; k++) {
        float hk = __shfl(h1, k, 32);   // broadcast within 32-lane group
        if (j < HID) h2 += hk * W2s[k * HID + j];
    }
    if (j < HID) {
        h2 = fmaxf(h2, 0.f);
        h2out[(size_t)r * HID + j] = h2;
    }
}

// ---------------- Kernel C: masked softmax via constant-fill + scatter -------
// Math: filtered row has >=3840 exact zeros; softmax(row)[i] is a per-row
// constant base_e/denom everywhere except move slots. So: compute only the
// <=256 move logits, dedupe duplicates for the denominator, stream the
// constant, scatter the move probabilities on top.
__global__ __launch_bounds__(256) void kmain(const int* __restrict__ moves,
                                             const float* __restrict__ b3,
                                             const float* __restrict__ W3T,
                                             const float* __restrict__ h2all,
                                             float* __restrict__ out) {
    __shared__ unsigned char claimed[OUT_DIM];  // 4 KB; NO init needed: only
                                                // slots that were written get read
    __shared__ float h2s[HID];
    __shared__ float red[8];

    int r = blockIdx.x;
    int t = threadIdx.x;

    if (t < HID) h2s[t] = h2all[(size_t)r * HID + t];
    int c = moves[(size_t)r * KMOV + t];
    __syncthreads();   // h2s visible

    // gather W3T column (24 contiguous floats), dot24 -> logit
    const float4* w = (const float4*)(W3T + c * HID);
    float4 a0 = w[0], a1 = w[1], a2 = w[2], a3 = w[3], a4 = w[4], a5 = w[5];
    float acc = b3[c];
    acc += a0.x*h2s[0] + a0.y*h2s[1] + a0.z*h2s[2]  + a0.w*h2s[3];
    acc += a1.x*h2s[4] + a1.y*h2s[5] + a1.z*h2s[6]  + a1.w*h2s[7];
    acc += a2.x*h2s[8] + a2.y*h2s[9] + a2.z*h2s[10] + a2.w*h2s[11];
    acc += a3.x*h2s[12]+ a3.y*h2s[13]+ a3.z*h2s[14] + a3.w*h2s[15];
    acc += a4.x*h2s[16]+ a4.y*h2s[17]+ a4.z*h2s[18] + a4.w*h2s[19];
    acc += a5.x*h2s[20]+ a5.y*h2s[21]+ a5.z*h2s[22] + a5.w*h2s[23];

    // claim slot c (any single writer wins; all readers of claimed[c] wrote it)
    claimed[c] = (unsigned char)t;

    // block max of logits (duplicates don't affect max)
    float m = acc;
    #pragma unroll
    for (int off = 32; off > 0; off >>= 1) m = fmaxf(m, __shfl_xor(m, off, 64));
    int wid = t >> 6;
    if ((t & 63) == 0) red[wid] = m;
    __syncthreads();   // orders claimed[] writes AND red[0..3]
    float mm = fmaxf(fmaxf(fmaxf(red[0], red[1]), fmaxf(red[2], red[3])), 0.f);

    float e      = __expf(acc - mm);   // native v_exp_f32 path
    float base_e = __expf(-mm);

    // denominator with duplicate moves counted once
    float contrib = (claimed[c] == (unsigned char)t) ? (e - base_e) : 0.f;
    float s = contrib;
    #pragma unroll
    for (int off = 32; off > 0; off >>= 1) s += __shfl_xor(s, off, 64);
    if ((t & 63) == 0) red[4 + wid] = s;
    __syncthreads();
    float denom = (float)OUT_DIM * base_e + (red[4] + red[5] + red[6] + red[7]);
    float inv = 1.0f / denom;
    float oc  = base_e * inv;

    // stream the per-row constant (coalesced float4)
    float4 ocv = make_float4(oc, oc, oc, oc);
    float4* out4 = (float4*)(out + (size_t)r * OUT_DIM);
    #pragma unroll
    for (int i = 0; i < 4; i++) out4[t + i * 256] = ocv;

    __syncthreads();   // drains vmcnt: fills complete before scatter overwrites

    // scatter move probabilities (duplicates write identical values: benign)
    out[(size_t)r * OUT_DIM + c] = e * inv;
}

extern "C" void kernel_launch(void* const* d_in, const int* in_sizes, int n_in,
                              void* d_out, int out_size, void* d_ws, size_t ws_size,
                              hipStream_t stream) {
    const float* x     = (const float*)d_in[0];
    const int*   moves = (const int*)  d_in[1];
    const float* W1    = (const float*)d_in[2];
    const float* b1    = (const float*)d_in[3];
    const float* W2    = (const float*)d_in[4];
    const float* b2    = (const float*)d_in[5];
    const float* W3    = (const float*)d_in[6];
    const float* b3    = (const float*)d_in[7];
    float* out = (float*)d_out;

    float* W3T = (float*)d_ws;                                   // 384 KB
    float* h2  = (float*)((char*)d_ws + OUT_DIM * HID * 4);      // 1.5 MB

    ktranspose<<<(OUT_DIM * HID + 255) / 256, 256, 0, stream>>>(W3, W3T);
    kmlp<<<NB / 8, 256, 0, stream>>>(x, W1, b1, W2, b2, h2);
    kmain<<<NB, 256, 0, stream>>>(moves, b3, W3T, h2, out);
}

// Round 4
// 342.954 us; speedup vs baseline: 1.0645x; 1.0645x over previous
//
#include <hip/hip_runtime.h>
#include <hip/hip_bf16.h>

#define IN_DIM 128
#define HID 24
#define OUT_DIM 4096
#define NB 16384
#define KMOV 256

#define TR_BLOCKS 384            // 384*256 == OUT_DIM*HID exactly
#define MLP_BLOCKS (NB / 8)      // 8 rows per block

// ---------------- Kernel 1: fused W3-transpose + 2-layer MLP -----------------
// Blocks [0,384): transpose W3 [24,4096] -> W3T [4096,24]
// Blocks [384, 384+2048): h2 = relu(relu(x@W1+b1)@W2+b2), 8 rows/block
__global__ __launch_bounds__(256) void kprep(const float* __restrict__ x,
                                             const float* __restrict__ W1,
                                             const float* __restrict__ b1,
                                             const float* __restrict__ W2,
                                             const float* __restrict__ b2,
                                             const float* __restrict__ W3,
                                             float* __restrict__ W3T,
                                             float* __restrict__ h2out) {
    __shared__ float W1s[IN_DIM * HID];   // 12 KB
    __shared__ float W2s[HID * HID];
    __shared__ float b1s[HID], b2s[HID];
    __shared__ float xs[8][IN_DIM];       // 4 KB

    int bid = blockIdx.x;
    int t = threadIdx.x;

    if (bid < TR_BLOCKS) {                // transpose path (whole block)
        int i = bid * 256 + t;            // i < OUT_DIM*HID always
        int c = i / HID;
        int k = i - c * HID;
        W3T[i] = W3[k * OUT_DIM + c];
        return;
    }

    // ---- MLP path ----
    for (int i = t; i < IN_DIM * HID; i += 256) W1s[i] = W1[i];
    for (int i = t; i < HID * HID; i += 256)    W2s[i] = W2[i];
    if (t < HID) { b1s[t] = b1[t]; b2s[t] = b2[t]; }
    int rbase = (bid - TR_BLOCKS) * 8;
    for (int i = t; i < 8 * IN_DIM; i += 256)
        xs[i >> 7][i & 127] = x[(size_t)rbase * IN_DIM + i];
    __syncthreads();

    int g = t >> 5;        // row group 0..7
    int j = t & 31;        // lane within group
    int r = rbase + g;

    float h1 = 0.f;
    if (j < HID) {
        h1 = b1s[j];
        #pragma unroll 8
        for (int i = 0; i < IN_DIM; i++) h1 += xs[g][i] * W1s[i * HID + j];
        h1 = fmaxf(h1, 0.f);
    }
    float h2 = (j < HID) ? b2s[j] : 0.f;
    #pragma unroll
    for (int k = 0; k < HID; k++) {
        float hk = __shfl(h1, k, 32);   // broadcast within 32-lane group
        if (j < HID) h2 += hk * W2s[k * HID + j];
    }
    if (j < HID) {
        h2 = fmaxf(h2, 0.f);
        h2out[(size_t)r * HID + j] = h2;
    }
}

// ---------------- Kernel 2: masked softmax via constant-fill + scatter -------
// Math: filtered row has >=3840 exact zeros; softmax(row)[i] is a per-row
// constant base_e/denom everywhere except move slots. Compute only the <=256
// move logits, dedupe duplicates for the denominator, stream the constant,
// scatter the move probabilities on top.
__global__ __launch_bounds__(256) void kmain(const int* __restrict__ moves,
                                             const float* __restrict__ b3,
                                             const float* __restrict__ W3T,
                                             const float* __restrict__ h2all,
                                             float* __restrict__ out) {
    __shared__ unsigned char claimed[OUT_DIM];  // 4 KB; no init needed: only
                                                // slots that were written get read
    __shared__ float h2s[HID];
    __shared__ float red[8];

    int r = blockIdx.x;
    int t = threadIdx.x;

    int c = moves[(size_t)r * KMOV + t];
    if (t < HID) h2s[t] = h2all[(size_t)r * HID + t];
    __syncthreads();   // h2s visible

    // gather W3T column (24 contiguous floats), dot24 -> logit
    const float4* w = (const float4*)(W3T + c * HID);
    float4 a0 = w[0], a1 = w[1], a2 = w[2], a3 = w[3], a4 = w[4], a5 = w[5];
    float acc = b3[c];
    acc += a0.x*h2s[0] + a0.y*h2s[1] + a0.z*h2s[2]  + a0.w*h2s[3];
    acc += a1.x*h2s[4] + a1.y*h2s[5] + a1.z*h2s[6]  + a1.w*h2s[7];
    acc += a2.x*h2s[8] + a2.y*h2s[9] + a2.z*h2s[10] + a2.w*h2s[11];
    acc += a3.x*h2s[12]+ a3.y*h2s[13]+ a3.z*h2s[14] + a3.w*h2s[15];
    acc += a4.x*h2s[16]+ a4.y*h2s[17]+ a4.z*h2s[18] + a4.w*h2s[19];
    acc += a5.x*h2s[20]+ a5.y*h2s[21]+ a5.z*h2s[22] + a5.w*h2s[23];

    // claim slot c (any single writer wins; every reader of claimed[c] wrote it)
    claimed[c] = (unsigned char)t;

    // block max of logits (duplicates don't affect max)
    float m = acc;
    #pragma unroll
    for (int off = 32; off > 0; off >>= 1) m = fmaxf(m, __shfl_xor(m, off, 64));
    int wid = t >> 6;
    if ((t & 63) == 0) red[wid] = m;
    __syncthreads();   // orders claimed[] writes AND red[0..3]
    float mm = fmaxf(fmaxf(fmaxf(red[0], red[1]), fmaxf(red[2], red[3])), 0.f);

    float e      = __expf(acc - mm);   // native v_exp_f32 path
    float base_e = __expf(-mm);

    // denominator with duplicate moves counted once
    float contrib = (claimed[c] == (unsigned char)t) ? (e - base_e) : 0.f;
    float s = contrib;
    #pragma unroll
    for (int off = 32; off > 0; off >>= 1) s += __shfl_xor(s, off, 64);
    if ((t & 63) == 0) red[4 + wid] = s;
    __syncthreads();
    float denom = (float)OUT_DIM * base_e + (red[4] + red[5] + red[6] + red[7]);
    float inv = 1.0f / denom;
    float oc  = base_e * inv;

    // stream the per-row constant (coalesced float4)
    float4 ocv = make_float4(oc, oc, oc, oc);
    float4* out4 = (float4*)(out + (size_t)r * OUT_DIM);
    #pragma unroll
    for (int i = 0; i < 4; i++) out4[t + i * 256] = ocv;

    __syncthreads();   // drains vmcnt: fills complete before scatter overwrites

    // scatter move probabilities (duplicates write identical values: benign)
    out[(size_t)r * OUT_DIM + c] = e * inv;
}

extern "C" void kernel_launch(void* const* d_in, const int* in_sizes, int n_in,
                              void* d_out, int out_size, void* d_ws, size_t ws_size,
                              hipStream_t stream) {
    const float* x     = (const float*)d_in[0];
    const int*   moves = (const int*)  d_in[1];
    const float* W1    = (const float*)d_in[2];
    const float* b1    = (const float*)d_in[3];
    const float* W2    = (const float*)d_in[4];
    const float* b2    = (const float*)d_in[5];
    const float* W3    = (const float*)d_in[6];
    const float* b3    = (const float*)d_in[7];
    float* out = (float*)d_out;

    float* W3T = (float*)d_ws;                                   // 384 KB
    float* h2  = (float*)((char*)d_ws + OUT_DIM * HID * 4);      // 1.5 MB

    kprep<<<TR_BLOCKS + MLP_BLOCKS, 256, 0, stream>>>(x, W1, b1, W2, b2, W3, W3T, h2);
    kmain<<<NB, 256, 0, stream>>>(moves, b3, W3T, h2, out);
}